// Round 2
// baseline (1750.759 us; speedup 1.0000x reference)
//
#include <hip/hip_runtime.h>

// ---------------------------------------------------------------------------
// HiggsAudio dual-FFN decoder layer, MI355X gfx950.
// B=2 S=2048 D=2048 H=16 HD=128 F=8192. fp32 in/out, bf16 MFMA internally.
// ---------------------------------------------------------------------------

#define BB 2
#define SS 2048
#define DD 2048
#define HH 16
#define HDD 128
#define FF 8192
#define TT (BB*SS)   // 4096 tokens

typedef unsigned short ushort_t;
typedef __bf16 bf16x8 __attribute__((ext_vector_type(8)));
typedef float f32x4 __attribute__((ext_vector_type(4)));

#define DEV static __device__ __forceinline__

DEV float bf2f(ushort_t u) { __bf16 b; __builtin_memcpy(&b, &u, 2); return (float)b; }
DEV ushort_t f2bf(float f) { __bf16 b = (__bf16)f; ushort_t u; __builtin_memcpy(&u, &b, 2); return u; }

DEV void gl_lds16(const ushort_t* g, ushort_t* l) {
    // async global->LDS, 16B per lane; LDS dest is wave-uniform base + lane*16
    __builtin_amdgcn_global_load_lds((const __attribute__((address_space(1))) void*)g,
                                     (__attribute__((address_space(3))) void*)l, 16, 0, 0);
}

// ---------------------------------------------------------------------------
// Normalize audio_out_mask to uint8[TT] regardless of upload dtype.
// If bool (1B/elem): bytes at i%4!=0 are ~random -> some nonzero.
// If int32 (4B/elem, values 0/1 LE): bytes at i%4!=0 are ALL zero.
// Single block; detection then per-element normalize (no OOB in taken path).
// ---------------------------------------------------------------------------
__global__ __launch_bounds__(256) void norm_mask(const unsigned char* __restrict__ in,
                                                 unsigned char* __restrict__ out) {
    __shared__ int flag;
    if (threadIdx.x == 0) flag = 0;
    __syncthreads();
    int any = 0;
    for (int i = threadIdx.x; i < TT; i += 256)
        if ((i & 3) != 0 && in[i] != 0) any = 1;
    if (any) atomicOr(&flag, 1);
    __syncthreads();
    const int is_byte = flag;
    for (int i = threadIdx.x; i < TT; i += 256) {
        unsigned char v;
        if (is_byte) v = (in[i] != 0);
        else         v = (((const int*)in)[i] != 0);
        out[i] = v;
    }
}

// ---------------------------------------------------------------------------
// fp32 [K][N] -> bf16 [N][K]  (transpose + convert), 32x32 tiles via LDS
// ---------------------------------------------------------------------------
__global__ __launch_bounds__(256) void convw(const float* __restrict__ in,
                                             ushort_t* __restrict__ out, int K, int N) {
    __shared__ float t[32][33];
    const int tx = threadIdx.x & 31, ty = threadIdx.x >> 5;
    const int n0 = blockIdx.x * 32, k0 = blockIdx.y * 32;
#pragma unroll
    for (int i = 0; i < 4; ++i)
        t[ty + 8 * i][tx] = in[(size_t)(k0 + ty + 8 * i) * N + n0 + tx];
    __syncthreads();
#pragma unroll
    for (int i = 0; i < 4; ++i)
        out[(size_t)(n0 + ty + 8 * i) * K + k0 + tx] = f2bf(t[tx][ty + 8 * i]);
}

// ---------------------------------------------------------------------------
// RMSNorm row kernel: fp32 [T][D] -> bf16 [T][D]  (256 thr/row, 8 elem/thr)
// ---------------------------------------------------------------------------
__global__ __launch_bounds__(256) void rmsnorm_k(const float* __restrict__ x,
                                                 const float* __restrict__ wt,
                                                 ushort_t* __restrict__ out) {
    const int row = blockIdx.x, tid = threadIdx.x;
    const float4* xr = (const float4*)(x + (size_t)row * DD);
    float4 v0 = xr[tid * 2], v1 = xr[tid * 2 + 1];
    float ss = v0.x * v0.x + v0.y * v0.y + v0.z * v0.z + v0.w * v0.w
             + v1.x * v1.x + v1.y * v1.y + v1.z * v1.z + v1.w * v1.w;
#pragma unroll
    for (int d = 1; d < 64; d <<= 1) ss += __shfl_xor(ss, d);
    __shared__ float red[4];
    if ((tid & 63) == 0) red[tid >> 6] = ss;
    __syncthreads();
    const float tot = red[0] + red[1] + red[2] + red[3];
    const float sc = rsqrtf(tot * (1.0f / DD) + 1e-5f);
    const float4* wr = (const float4*)wt;
    float4 w0 = wr[tid * 2], w1 = wr[tid * 2 + 1];
    ushort_t* o = out + (size_t)row * DD + tid * 8;
    o[0] = f2bf(v0.x * sc * w0.x); o[1] = f2bf(v0.y * sc * w0.y);
    o[2] = f2bf(v0.z * sc * w0.z); o[3] = f2bf(v0.w * sc * w0.w);
    o[4] = f2bf(v1.x * sc * w1.x); o[5] = f2bf(v1.y * sc * w1.y);
    o[6] = f2bf(v1.z * sc * w1.z); o[7] = f2bf(v1.w * sc * w1.w);
}

// ---------------------------------------------------------------------------
// RoPE cos/sin table: [S][64] each
// ---------------------------------------------------------------------------
__global__ __launch_bounds__(256) void rope_tab(float* __restrict__ cosb,
                                                float* __restrict__ sinb) {
    const int idx = blockIdx.x * 256 + threadIdx.x;  // < 2048*64
    const int s = idx >> 6, i = idx & 63;
    const float inv = powf(10000.0f, -(float)i * (1.0f / 64.0f));
    const float ang = (float)s * inv;
    cosb[idx] = cosf(ang);
    sinb[idx] = sinf(ang);
}

// RoPE in-place on bf16 [T][H*HD]; one thread per (row, head, d<64) pair
__global__ __launch_bounds__(256) void rope_apply(ushort_t* __restrict__ x,
                                                  const float* __restrict__ cosb,
                                                  const float* __restrict__ sinb) {
    const int gid = blockIdx.x * 256 + threadIdx.x;  // < 4096*1024
    const int row = gid >> 10, p = gid & 1023;
    const int h = p >> 6, d = p & 63;
    const int s = row & (SS - 1);
    const size_t base = (size_t)row * DD + h * HDD + d;
    const float x1 = bf2f(x[base]), x2 = bf2f(x[base + 64]);
    const float c = cosb[s * 64 + d], sn = sinb[s * 64 + d];
    x[base]      = f2bf(x1 * c - x2 * sn);
    x[base + 64] = f2bf(x2 * c + x1 * sn);
}

// ---------------------------------------------------------------------------
// NT bf16 GEMM, 128x128 tile, BK=32, 4 waves (m97 structure).
// A [M][K] bf16 row-major, Bt [N][K] bf16 row-major.
// EPI: 0 = bf16 C[M][N]
//      1 = bf16 V^T write into [b][h][d][s]
//      2 = fp32 C = resid + acc   (wo projection)
//      3 = fp32 C += acc, only rows with mask[r]==target  (down proj)
// ---------------------------------------------------------------------------
template <int EPI>
__global__ __launch_bounds__(256, 2) void gemm_nt(
    const ushort_t* __restrict__ A, const ushort_t* __restrict__ Bt,
    int M, int N, int K, void* __restrict__ C,
    const float* __restrict__ resid, const unsigned char* __restrict__ mask, int target) {
    __shared__ ushort_t As[128 * 32];
    __shared__ ushort_t Bs[128 * 32];
    const int tid = threadIdx.x;
    const int w = tid >> 6, lane = tid & 63;
    const int m0 = blockIdx.y * 128, n0 = blockIdx.x * 128;
    const int wr = w >> 1, wc = w & 1;
    f32x4 acc[4][4] = {};
    const ushort_t* gA = A + (size_t)m0 * K;
    const ushort_t* gB = Bt + (size_t)n0 * K;
    // staging: chunk c = i*256 + tid covers tile row c>>2, elems (c&3)*8..+7
    const int c0 = tid, c1 = 256 + tid;
    const int r0 = c0 >> 2, o0 = (c0 & 3) * 8;
    const int r1 = c1 >> 2, o1 = (c1 & 3) * 8;
    ushort_t* lA0 = &As[(w * 64) * 8];
    ushort_t* lA1 = &As[(256 + w * 64) * 8];
    ushort_t* lB0 = &Bs[(w * 64) * 8];
    ushort_t* lB1 = &Bs[(256 + w * 64) * 8];
    for (int k0 = 0; k0 < K; k0 += 32) {
        __syncthreads();
        gl_lds16(gA + (size_t)r0 * K + k0 + o0, lA0);
        gl_lds16(gA + (size_t)r1 * K + k0 + o1, lA1);
        gl_lds16(gB + (size_t)r0 * K + k0 + o0, lB0);
        gl_lds16(gB + (size_t)r1 * K + k0 + o1, lB1);
        asm volatile("s_waitcnt vmcnt(0)" ::: "memory");
        __syncthreads();
        const int ko = (lane >> 4) * 8;
        const int ra = wr * 64 + (lane & 15);
        const int rb = wc * 64 + (lane & 15);
        bf16x8 af[4], bfv[4];
#pragma unroll
        for (int mi = 0; mi < 4; ++mi) af[mi] = *(const bf16x8*)&As[(ra + mi * 16) * 32 + ko];
#pragma unroll
        for (int ni = 0; ni < 4; ++ni) bfv[ni] = *(const bf16x8*)&Bs[(rb + ni * 16) * 32 + ko];
#pragma unroll
        for (int mi = 0; mi < 4; ++mi)
#pragma unroll
            for (int ni = 0; ni < 4; ++ni)
                acc[mi][ni] = __builtin_amdgcn_mfma_f32_16x16x32_bf16(af[mi], bfv[ni], acc[mi][ni], 0, 0, 0);
    }
    // epilogue: C/D layout col = lane&15, row = (lane>>4)*4 + j  [m89-verified]
    const int cl = lane & 15, r4 = (lane >> 4) * 4;
#pragma unroll
    for (int mi = 0; mi < 4; ++mi)
#pragma unroll
        for (int ni = 0; ni < 4; ++ni)
#pragma unroll
            for (int j = 0; j < 4; ++j) {
                const int r = m0 + wr * 64 + mi * 16 + r4 + j;
                const int c = n0 + wc * 64 + ni * 16 + cl;
                const float v = acc[mi][ni][j];
                if (EPI == 0) {
                    ((ushort_t*)C)[(size_t)r * N + c] = f2bf(v);
                } else if (EPI == 1) {
                    const int b = r >> 11, s = r & (SS - 1), h = c >> 7, d = c & 127;
                    ((ushort_t*)C)[(((size_t)(b * HH + h) * HDD + d) << 11) + s] = f2bf(v);
                } else if (EPI == 2) {
                    const size_t idx = (size_t)r * N + c;
                    ((float*)C)[idx] = resid[idx] + v;
                } else {
                    if ((mask[r] != 0) == (target != 0)) {
                        float* p = (float*)C + (size_t)r * DD + c;
                        *p = *p + v;
                    }
                }
            }
}

// ---------------------------------------------------------------------------
// Fused gate+up GEMM: per block 128(M) x 64(N per matrix), both B matrices;
// epilogue writes act = silu(g)*u as bf16 [T][F].
// ---------------------------------------------------------------------------
__global__ __launch_bounds__(256, 2) void gemm_gateup(
    const ushort_t* __restrict__ A, const ushort_t* __restrict__ Bg,
    const ushort_t* __restrict__ Bu, ushort_t* __restrict__ act) {
    __shared__ ushort_t As[128 * 32];
    __shared__ ushort_t Bgs[64 * 32];
    __shared__ ushort_t Bus[64 * 32];
    const int tid = threadIdx.x, w = tid >> 6, lane = tid & 63;
    const int m0 = blockIdx.y * 128, n0 = blockIdx.x * 64;
    const int wr = w >> 1, wc = w & 1;
    f32x4 ag[4][2] = {}, au[4][2] = {};
    const ushort_t* gA = A + (size_t)m0 * DD;
    const ushort_t* gG = Bg + (size_t)n0 * DD;
    const ushort_t* gU = Bu + (size_t)n0 * DD;
    const int c0 = tid, c1 = 256 + tid;
    const int rA0 = c0 >> 2, oA0 = (c0 & 3) * 8;
    const int rA1 = c1 >> 2, oA1 = (c1 & 3) * 8;
    ushort_t* lA0 = &As[(w * 64) * 8];
    ushort_t* lA1 = &As[(256 + w * 64) * 8];
    ushort_t* lG = &Bgs[(w * 64) * 8];
    ushort_t* lU = &Bus[(w * 64) * 8];
    for (int k0 = 0; k0 < DD; k0 += 32) {
        __syncthreads();
        gl_lds16(gA + (size_t)rA0 * DD + k0 + oA0, lA0);
        gl_lds16(gA + (size_t)rA1 * DD + k0 + oA1, lA1);
        gl_lds16(gG + (size_t)rA0 * DD + k0 + oA0, lG);
        gl_lds16(gU + (size_t)rA0 * DD + k0 + oA0, lU);
        asm volatile("s_waitcnt vmcnt(0)" ::: "memory");
        __syncthreads();
        const int ko = (lane >> 4) * 8;
        const int ra = wr * 64 + (lane & 15);
        const int rb = wc * 32 + (lane & 15);
        bf16x8 af[4], bg[2], bu[2];
#pragma unroll
        for (int mi = 0; mi < 4; ++mi) af[mi] = *(const bf16x8*)&As[(ra + mi * 16) * 32 + ko];
#pragma unroll
        for (int ni = 0; ni < 2; ++ni) {
            bg[ni] = *(const bf16x8*)&Bgs[(rb + ni * 16) * 32 + ko];
            bu[ni] = *(const bf16x8*)&Bus[(rb + ni * 16) * 32 + ko];
        }
#pragma unroll
        for (int mi = 0; mi < 4; ++mi)
#pragma unroll
            for (int ni = 0; ni < 2; ++ni) {
                ag[mi][ni] = __builtin_amdgcn_mfma_f32_16x16x32_bf16(af[mi], bg[ni], ag[mi][ni], 0, 0, 0);
                au[mi][ni] = __builtin_amdgcn_mfma_f32_16x16x32_bf16(af[mi], bu[ni], au[mi][ni], 0, 0, 0);
            }
    }
    const int cl = lane & 15, r4 = (lane >> 4) * 4;
#pragma unroll
    for (int mi = 0; mi < 4; ++mi)
#pragma unroll
        for (int ni = 0; ni < 2; ++ni)
#pragma unroll
            for (int j = 0; j < 4; ++j) {
                const int r = m0 + wr * 64 + mi * 16 + r4 + j;
                const int c = n0 + wc * 32 + ni * 16 + cl;
                const float g = ag[mi][ni][j], u = au[mi][ni][j];
                const float sv = g / (1.0f + __expf(-g)) * u;
                act[(size_t)r * FF + c] = f2bf(sv);
            }
}

// ---------------------------------------------------------------------------
// Causal flash attention. grid (S/64, B*H). 4 waves, each owns 16 q-rows.
// qb,kb: bf16 [T][H*HD] (roped). vt: bf16 [b][h][d][s]. ctx out: bf16 [T][H*HD].
// ---------------------------------------------------------------------------
__global__ __launch_bounds__(256, 2) void attn_k(
    const ushort_t* __restrict__ qb, const ushort_t* __restrict__ kb,
    const ushort_t* __restrict__ vt, ushort_t* __restrict__ ctx) {
    __shared__ ushort_t Ks[64 * 128];   // [sk][d]
    __shared__ ushort_t Vs[128 * 64];   // [d][sk]
    __shared__ ushort_t Pw[4][16 * 64]; // per-wave P transpose buffer
    const int tid = threadIdx.x, w = tid >> 6, lane = tid & 63;
    const int qt = blockIdx.x, bh = blockIdx.y, b = bh >> 4, h = bh & 15;
    const int q0 = qt * 64 + w * 16;
    bf16x8 aq[4];
    {
        const ushort_t* qr = qb + ((size_t)(b * SS + q0 + (lane & 15))) * DD + h * HDD + (lane >> 4) * 8;
#pragma unroll
        for (int ko = 0; ko < 4; ++ko) aq[ko] = *(const bf16x8*)(qr + ko * 32);
    }
    f32x4 o[8] = {};
    float mrow[4] = {-3e38f, -3e38f, -3e38f, -3e38f};
    float lrow[4] = {};
    for (int kt = 0; kt <= qt; ++kt) {
        const int sk0 = kt * 64;
        __syncthreads();
#pragma unroll
        for (int i = 0; i < 4; ++i) {
            const int c = i * 256 + tid;
            gl_lds16(kb + ((size_t)(b * SS + sk0 + (c >> 4))) * DD + h * HDD + (c & 15) * 8,
                     &Ks[(i * 256 + w * 64) * 8]);
        }
#pragma unroll
        for (int i = 0; i < 4; ++i) {
            const int c = i * 256 + tid;
            gl_lds16(vt + ((size_t)((b * HH + h) * HDD + (c >> 3))) * SS + sk0 + (c & 7) * 8,
                     &Vs[(i * 256 + w * 64) * 8]);
        }
        asm volatile("s_waitcnt vmcnt(0)" ::: "memory");
        __syncthreads();
        // S = Q K^T  (16 q-rows x 64 k-cols)
        f32x4 s[4] = {};
#pragma unroll
        for (int ko = 0; ko < 4; ++ko)
#pragma unroll
            for (int ni = 0; ni < 4; ++ni) {
                bf16x8 bk = *(const bf16x8*)&Ks[(ni * 16 + (lane & 15)) * 128 + ko * 32 + (lane >> 4) * 8];
                s[ni] = __builtin_amdgcn_mfma_f32_16x16x32_bf16(aq[ko], bk, s[ni], 0, 0, 0);
            }
        const float scale = 0.08838834764831843f;  // 1/sqrt(128)
        const bool diag = (kt == qt);
#pragma unroll
        for (int ni = 0; ni < 4; ++ni)
#pragma unroll
            for (int j = 0; j < 4; ++j) {
                float v = s[ni][j] * scale;
                if (diag) {
                    const int kg = ni * 16 + (lane & 15);
                    const int qg = w * 16 + (lane >> 4) * 4 + j;
                    if (kg > qg) v = -1e30f;
                }
                s[ni][j] = v;
            }
        // online softmax per row (rows live in (lane>>4) groups; reduce over 16 lanes)
#pragma unroll
        for (int j = 0; j < 4; ++j) {
            float tm = fmaxf(fmaxf(s[0][j], s[1][j]), fmaxf(s[2][j], s[3][j]));
#pragma unroll
            for (int dd = 1; dd < 16; dd <<= 1) tm = fmaxf(tm, __shfl_xor(tm, dd));
            const float mn = fmaxf(mrow[j], tm);
            const float corr = __expf(mrow[j] - mn);
            float sum = 0.f;
#pragma unroll
            for (int ni = 0; ni < 4; ++ni) {
                const float p = __expf(s[ni][j] - mn);
                s[ni][j] = p;
                sum += p;
            }
#pragma unroll
            for (int dd = 1; dd < 16; dd <<= 1) sum += __shfl_xor(sum, dd);
            lrow[j] = lrow[j] * corr + sum;
            mrow[j] = mn;
#pragma unroll
            for (int di = 0; di < 8; ++di) o[di][j] *= corr;
        }
        // P -> per-wave LDS (transpose to A-frag layout), then PV
#pragma unroll
        for (int ni = 0; ni < 4; ++ni)
#pragma unroll
            for (int j = 0; j < 4; ++j)
                Pw[w][((lane >> 4) * 4 + j) * 64 + ni * 16 + (lane & 15)] = f2bf(s[ni][j]);
#pragma unroll
        for (int ks = 0; ks < 2; ++ks) {
            bf16x8 pa = *(const bf16x8*)&Pw[w][(lane & 15) * 64 + ks * 32 + (lane >> 4) * 8];
#pragma unroll
            for (int di = 0; di < 8; ++di) {
                bf16x8 bv = *(const bf16x8*)&Vs[(di * 16 + (lane & 15)) * 64 + ks * 32 + (lane >> 4) * 8];
                o[di] = __builtin_amdgcn_mfma_f32_16x16x32_bf16(pa, bv, o[di], 0, 0, 0);
            }
        }
    }
    float inv[4];
#pragma unroll
    for (int j = 0; j < 4; ++j) inv[j] = 1.0f / lrow[j];
#pragma unroll
    for (int di = 0; di < 8; ++di)
#pragma unroll
        for (int j = 0; j < 4; ++j) {
            const int r = q0 + (lane >> 4) * 4 + j;
            ctx[((size_t)(b * SS + r)) * DD + h * HDD + di * 16 + (lane & 15)] = f2bf(o[di][j] * inv[j]);
        }
}

// ---------------------------------------------------------------------------
extern "C" void kernel_launch(void* const* d_in, const int* in_sizes, int n_in,
                              void* d_out, int out_size, void* d_ws, size_t ws_size,
                              hipStream_t stream) {
    (void)in_sizes; (void)n_in; (void)out_size; (void)ws_size;
    const float* hs  = (const float*)d_in[0];
    const unsigned char* mask_raw = (const unsigned char*)d_in[1];  // bool OR int32 — normalized below
    const float* wq  = (const float*)d_in[2];
    const float* wk  = (const float*)d_in[3];
    const float* wv  = (const float*)d_in[4];
    const float* wo  = (const float*)d_in[5];
    const float* iln = (const float*)d_in[6];
    const float* pln = (const float*)d_in[7];
    const float* aln = (const float*)d_in[8];
    const float* wgt = (const float*)d_in[9];
    const float* wut = (const float*)d_in[10];
    const float* wdt = (const float*)d_in[11];
    const float* wga = (const float*)d_in[12];
    const float* wua = (const float*)d_in[13];
    const float* wda = (const float*)d_in[14];

    const size_t SZ_W1 = (size_t)DD * DD * 2;       // 8 MB  (bf16 2048x2048)
    const size_t SZ_W2 = (size_t)DD * FF * 2;       // 32 MB (bf16 8192x2048)
    const size_t SZ_A  = (size_t)TT * DD * 2;       // 16 MB (bf16 4096x2048)

    char* ws = (char*)d_ws;
    size_t off = 0;
    auto take = [&](size_t n) { char* p = ws + off; off += n; return p; };
    ushort_t* wq_t  = (ushort_t*)take(SZ_W1);
    ushort_t* wk_t  = (ushort_t*)take(SZ_W1);
    ushort_t* wv_t  = (ushort_t*)take(SZ_W1);
    ushort_t* wo_t  = (ushort_t*)take(SZ_W1);
    ushort_t* wg_tb = (ushort_t*)take(SZ_W2);
    ushort_t* wu_tb = (ushort_t*)take(SZ_W2);
    ushort_t* wd_tb = (ushort_t*)take(SZ_W2);
    ushort_t* wg_ab = (ushort_t*)take(SZ_W2);
    ushort_t* wu_ab = (ushort_t*)take(SZ_W2);
    ushort_t* wd_ab = (ushort_t*)take(SZ_W2);
    ushort_t* h_bf  = (ushort_t*)take(SZ_A);
    ushort_t* qb    = (ushort_t*)take(SZ_A);
    ushort_t* kb    = (ushort_t*)take(SZ_A);
    ushort_t* vt    = (ushort_t*)take(SZ_A);
    ushort_t* ctx   = (ushort_t*)take(SZ_A);
    ushort_t* hn    = (ushort_t*)take(SZ_A);
    float* cosb = (float*)take((size_t)SS * 64 * 4);
    float* sinb = (float*)take((size_t)SS * 64 * 4);
    unsigned char* mask = (unsigned char*)take(TT);
    ushort_t* act = qb;  // overlay: act (64MB) reuses qb,kb,vt,ctx after attention

    const dim3 blk(256);

    norm_mask<<<1, blk, 0, stream>>>(mask_raw, mask);

    // --- weight convert + transpose to bf16 [N][K] ---
    convw<<<dim3(DD / 32, DD / 32), blk, 0, stream>>>(wq, wq_t, DD, DD);
    convw<<<dim3(DD / 32, DD / 32), blk, 0, stream>>>(wk, wk_t, DD, DD);
    convw<<<dim3(DD / 32, DD / 32), blk, 0, stream>>>(wv, wv_t, DD, DD);
    convw<<<dim3(DD / 32, DD / 32), blk, 0, stream>>>(wo, wo_t, DD, DD);
    convw<<<dim3(FF / 32, DD / 32), blk, 0, stream>>>(wgt, wg_tb, DD, FF);
    convw<<<dim3(FF / 32, DD / 32), blk, 0, stream>>>(wut, wu_tb, DD, FF);
    convw<<<dim3(DD / 32, FF / 32), blk, 0, stream>>>(wdt, wd_tb, FF, DD);
    convw<<<dim3(FF / 32, DD / 32), blk, 0, stream>>>(wga, wg_ab, DD, FF);
    convw<<<dim3(FF / 32, DD / 32), blk, 0, stream>>>(wua, wu_ab, DD, FF);
    convw<<<dim3(DD / 32, FF / 32), blk, 0, stream>>>(wda, wd_ab, FF, DD);

    rope_tab<<<(SS * 64) / 256, blk, 0, stream>>>(cosb, sinb);

    // --- attention block ---
    rmsnorm_k<<<TT, blk, 0, stream>>>(hs, iln, h_bf);
    gemm_nt<0><<<dim3(DD / 128, TT / 128), blk, 0, stream>>>(h_bf, wq_t, TT, DD, DD, qb, nullptr, nullptr, 0);
    gemm_nt<0><<<dim3(DD / 128, TT / 128), blk, 0, stream>>>(h_bf, wk_t, TT, DD, DD, kb, nullptr, nullptr, 0);
    gemm_nt<1><<<dim3(DD / 128, TT / 128), blk, 0, stream>>>(h_bf, wv_t, TT, DD, DD, vt, nullptr, nullptr, 0);
    rope_apply<<<(TT * 1024) / 256, blk, 0, stream>>>(qb, cosb, sinb);
    rope_apply<<<(TT * 1024) / 256, blk, 0, stream>>>(kb, cosb, sinb);
    attn_k<<<dim3(SS / 64, BB * HH), blk, 0, stream>>>(qb, kb, vt, ctx);
    // d_out = hidden = residual + ctx @ wo
    gemm_nt<2><<<dim3(DD / 128, TT / 128), blk, 0, stream>>>(ctx, wo_t, TT, DD, DD, d_out, hs, nullptr, 0);

    // --- dual FFN (dense compute, row-masked accumulate) ---
    // text branch (mask == 0)
    rmsnorm_k<<<TT, blk, 0, stream>>>((const float*)d_out, pln, hn);
    gemm_gateup<<<dim3(FF / 64, TT / 128), blk, 0, stream>>>(hn, wg_tb, wu_tb, act);
    gemm_nt<3><<<dim3(DD / 128, TT / 128), blk, 0, stream>>>(act, wd_tb, TT, DD, FF, d_out, nullptr, mask, 0);
    // audio branch (mask == 1); text rows in hn/act are garbage-but-finite and never written
    rmsnorm_k<<<TT, blk, 0, stream>>>((const float*)d_out, aln, hn);
    gemm_gateup<<<dim3(FF / 64, TT / 128), blk, 0, stream>>>(hn, wg_ab, wu_ab, act);
    gemm_nt<3><<<dim3(DD / 128, TT / 128), blk, 0, stream>>>(act, wd_ab, TT, DD, FF, d_out, nullptr, mask, 1);
}

// Round 3
// 1297.904 us; speedup vs baseline: 1.3489x; 1.3489x over previous
//
#include <hip/hip_runtime.h>

// ---------------------------------------------------------------------------
// HiggsAudio dual-FFN decoder layer, MI355X gfx950.
// B=2 S=2048 D=2048 H=16 HD=128 F=8192. fp32 in/out, bf16 MFMA internally.
// R3: token compaction — FFN computed once per token (routed), not dense x2.
// ---------------------------------------------------------------------------

#define BB 2
#define SS 2048
#define DD 2048
#define HH 16
#define HDD 128
#define FF 8192
#define TT (BB*SS)   // 4096 tokens
#define RPAD 4352    // max compacted rows (34 tiles of 128)

typedef unsigned short ushort_t;
typedef __bf16 bf16x8 __attribute__((ext_vector_type(8)));
typedef float f32x4 __attribute__((ext_vector_type(4)));

#define DEV static __device__ __forceinline__

DEV float bf2f(ushort_t u) { __bf16 b; __builtin_memcpy(&b, &u, 2); return (float)b; }
DEV ushort_t f2bf(float f) { __bf16 b = (__bf16)f; ushort_t u; __builtin_memcpy(&u, &b, 2); return u; }

DEV void gl_lds16(const ushort_t* g, ushort_t* l) {
    // async global->LDS, 16B per lane; LDS dest is wave-uniform base + lane*16
    __builtin_amdgcn_global_load_lds((const __attribute__((address_space(1))) void*)g,
                                     (__attribute__((address_space(3))) void*)l, 16, 0, 0);
}

// ---------------------------------------------------------------------------
// Normalize audio_out_mask to uint8[TT] regardless of upload dtype (bool/int32).
// ---------------------------------------------------------------------------
__global__ __launch_bounds__(256) void norm_mask(const unsigned char* __restrict__ in,
                                                 unsigned char* __restrict__ out) {
    __shared__ int flag;
    if (threadIdx.x == 0) flag = 0;
    __syncthreads();
    int any = 0;
    for (int i = threadIdx.x; i < TT; i += 256)
        if ((i & 3) != 0 && in[i] != 0) any = 1;
    if (any) atomicOr(&flag, 1);
    __syncthreads();
    const int is_byte = flag;
    for (int i = threadIdx.x; i < TT; i += 256) {
        unsigned char v;
        if (is_byte) v = (in[i] != 0);
        else         v = (((const int*)in)[i] != 0);
        out[i] = v;
    }
}

// ---------------------------------------------------------------------------
// Stable partition of token ids by mask: [text | pad(-1) | audio | pad(-1)].
// header: [0]=Nt [1]=A0 (audio base, 128-aligned) [2]=Na [3]=live_rows.
// Single block, deterministic.
// ---------------------------------------------------------------------------
__global__ __launch_bounds__(256) void partition_k(const unsigned char* __restrict__ mask,
                                                   int* __restrict__ perm,
                                                   int* __restrict__ header) {
    __shared__ int ct[256], ca[256], st[256], sa[256];
    __shared__ int Nt_s, Na_s;
    const int tid = threadIdx.x;
    int c0 = 0, c1 = 0;
#pragma unroll
    for (int i = 0; i < 16; ++i) {
        if (mask[tid * 16 + i]) c1++; else c0++;
    }
    ct[tid] = c0; ca[tid] = c1;
    __syncthreads();
    if (tid == 0) {
        int at = 0, aa = 0;
        for (int i = 0; i < 256; ++i) {
            st[i] = at; at += ct[i];
            sa[i] = aa; aa += ca[i];
        }
        Nt_s = at; Na_s = aa;
    }
    __syncthreads();
    const int Nt = Nt_s, Na = Na_s;
    const int A0 = (Nt + 127) & ~127;
    const int live = A0 + ((Na + 127) & ~127);
    int pt = st[tid], pa = A0 + sa[tid];
#pragma unroll
    for (int i = 0; i < 16; ++i) {
        const int r = tid * 16 + i;
        if (mask[r]) perm[pa++] = r; else perm[pt++] = r;
    }
    for (int i = Nt + tid; i < A0; i += 256) perm[i] = -1;
    for (int i = A0 + Na + tid; i < RPAD; i += 256) perm[i] = -1;
    if (tid == 0) { header[0] = Nt; header[1] = A0; header[2] = Na; header[3] = live; }
}

// ---------------------------------------------------------------------------
// fp32 [K][N] -> bf16 [N][K]  (transpose + convert), 32x32 tiles via LDS
// ---------------------------------------------------------------------------
__global__ __launch_bounds__(256) void convw(const float* __restrict__ in,
                                             ushort_t* __restrict__ out, int K, int N) {
    __shared__ float t[32][33];
    const int tx = threadIdx.x & 31, ty = threadIdx.x >> 5;
    const int n0 = blockIdx.x * 32, k0 = blockIdx.y * 32;
#pragma unroll
    for (int i = 0; i < 4; ++i)
        t[ty + 8 * i][tx] = in[(size_t)(k0 + ty + 8 * i) * N + n0 + tx];
    __syncthreads();
#pragma unroll
    for (int i = 0; i < 4; ++i)
        out[(size_t)(n0 + ty + 8 * i) * K + k0 + tx] = f2bf(t[tx][ty + 8 * i]);
}

// ---------------------------------------------------------------------------
// RMSNorm: fp32 [T][D] row -> bf16 row (256 thr/row, 8 elem/thr)
// ---------------------------------------------------------------------------
__global__ __launch_bounds__(256) void rmsnorm_k(const float* __restrict__ x,
                                                 const float* __restrict__ wt,
                                                 ushort_t* __restrict__ out) {
    const int row = blockIdx.x, tid = threadIdx.x;
    const float4* xr = (const float4*)(x + (size_t)row * DD);
    float4 v0 = xr[tid * 2], v1 = xr[tid * 2 + 1];
    float ss = v0.x * v0.x + v0.y * v0.y + v0.z * v0.z + v0.w * v0.w
             + v1.x * v1.x + v1.y * v1.y + v1.z * v1.z + v1.w * v1.w;
#pragma unroll
    for (int d = 1; d < 64; d <<= 1) ss += __shfl_xor(ss, d);
    __shared__ float red[4];
    if ((tid & 63) == 0) red[tid >> 6] = ss;
    __syncthreads();
    const float tot = red[0] + red[1] + red[2] + red[3];
    const float sc = rsqrtf(tot * (1.0f / DD) + 1e-5f);
    const float4* wr = (const float4*)wt;
    float4 w0 = wr[tid * 2], w1 = wr[tid * 2 + 1];
    ushort_t* o = out + (size_t)row * DD + tid * 8;
    o[0] = f2bf(v0.x * sc * w0.x); o[1] = f2bf(v0.y * sc * w0.y);
    o[2] = f2bf(v0.z * sc * w0.z); o[3] = f2bf(v0.w * sc * w0.w);
    o[4] = f2bf(v1.x * sc * w1.x); o[5] = f2bf(v1.y * sc * w1.y);
    o[6] = f2bf(v1.z * sc * w1.z); o[7] = f2bf(v1.w * sc * w1.w);
}

// ---------------------------------------------------------------------------
// Gathered RMSNorm into compacted rows: out[i] = rmsnorm(x[perm[i]], w_branch)
// ---------------------------------------------------------------------------
__global__ __launch_bounds__(256) void rmsnorm_gather(const float* __restrict__ x,
                                                      const float* __restrict__ wt_text,
                                                      const float* __restrict__ wt_audio,
                                                      const int* __restrict__ perm,
                                                      const int* __restrict__ header,
                                                      ushort_t* __restrict__ out) {
    const int i = blockIdx.x, tid = threadIdx.x;
    const int p = perm[i];
    ushort_t* o = out + (size_t)i * DD + tid * 8;
    if (p < 0) {
#pragma unroll
        for (int j = 0; j < 8; ++j) o[j] = 0;
        return;
    }
    const float* wt = (i < header[1]) ? wt_text : wt_audio;
    const float4* xr = (const float4*)(x + (size_t)p * DD);
    float4 v0 = xr[tid * 2], v1 = xr[tid * 2 + 1];
    float ss = v0.x * v0.x + v0.y * v0.y + v0.z * v0.z + v0.w * v0.w
             + v1.x * v1.x + v1.y * v1.y + v1.z * v1.z + v1.w * v1.w;
#pragma unroll
    for (int d = 1; d < 64; d <<= 1) ss += __shfl_xor(ss, d);
    __shared__ float red[4];
    if ((tid & 63) == 0) red[tid >> 6] = ss;
    __syncthreads();
    const float tot = red[0] + red[1] + red[2] + red[3];
    const float sc = rsqrtf(tot * (1.0f / DD) + 1e-5f);
    const float4* wr = (const float4*)wt;
    float4 w0 = wr[tid * 2], w1 = wr[tid * 2 + 1];
    o[0] = f2bf(v0.x * sc * w0.x); o[1] = f2bf(v0.y * sc * w0.y);
    o[2] = f2bf(v0.z * sc * w0.z); o[3] = f2bf(v0.w * sc * w0.w);
    o[4] = f2bf(v1.x * sc * w1.x); o[5] = f2bf(v1.y * sc * w1.y);
    o[6] = f2bf(v1.z * sc * w1.z); o[7] = f2bf(v1.w * sc * w1.w);
}

// ---------------------------------------------------------------------------
// RoPE cos/sin table: [S][64] each
// ---------------------------------------------------------------------------
__global__ __launch_bounds__(256) void rope_tab(float* __restrict__ cosb,
                                                float* __restrict__ sinb) {
    const int idx = blockIdx.x * 256 + threadIdx.x;  // < 2048*64
    const int s = idx >> 6, i = idx & 63;
    const float inv = powf(10000.0f, -(float)i * (1.0f / 64.0f));
    const float ang = (float)s * inv;
    cosb[idx] = cosf(ang);
    sinb[idx] = sinf(ang);
}

// RoPE in-place on bf16 [T][H*HD]; one thread per (row, head, d<64) pair
__global__ __launch_bounds__(256) void rope_apply(ushort_t* __restrict__ x,
                                                  const float* __restrict__ cosb,
                                                  const float* __restrict__ sinb) {
    const int gid = blockIdx.x * 256 + threadIdx.x;  // < 4096*1024
    const int row = gid >> 10, p = gid & 1023;
    const int h = p >> 6, d = p & 63;
    const int s = row & (SS - 1);
    const size_t base = (size_t)row * DD + h * HDD + d;
    const float x1 = bf2f(x[base]), x2 = bf2f(x[base + 64]);
    const float c = cosb[s * 64 + d], sn = sinb[s * 64 + d];
    x[base]      = f2bf(x1 * c - x2 * sn);
    x[base + 64] = f2bf(x2 * c + x1 * sn);
}

// ---------------------------------------------------------------------------
// NT bf16 GEMM, 128x128 tile, BK=32, 4 waves (m97 structure).
// A [M][K] bf16 row-major, Bt [N][K] bf16 row-major.
// EPI: 0 = bf16 C[M][N]
//      1 = bf16 V^T write into [b][h][d][s]
//      2 = fp32 C = resid + acc   (wo projection)
// ---------------------------------------------------------------------------
template <int EPI>
__global__ __launch_bounds__(256, 2) void gemm_nt(
    const ushort_t* __restrict__ A, const ushort_t* __restrict__ Bt,
    int M, int N, int K, void* __restrict__ C,
    const float* __restrict__ resid) {
    __shared__ ushort_t As[128 * 32];
    __shared__ ushort_t Bs[128 * 32];
    const int tid = threadIdx.x;
    const int w = tid >> 6, lane = tid & 63;
    const int m0 = blockIdx.y * 128, n0 = blockIdx.x * 128;
    const int wr = w >> 1, wc = w & 1;
    f32x4 acc[4][4] = {};
    const ushort_t* gA = A + (size_t)m0 * K;
    const ushort_t* gB = Bt + (size_t)n0 * K;
    const int c0 = tid, c1 = 256 + tid;
    const int r0 = c0 >> 2, o0 = (c0 & 3) * 8;
    const int r1 = c1 >> 2, o1 = (c1 & 3) * 8;
    ushort_t* lA0 = &As[(w * 64) * 8];
    ushort_t* lA1 = &As[(256 + w * 64) * 8];
    ushort_t* lB0 = &Bs[(w * 64) * 8];
    ushort_t* lB1 = &Bs[(256 + w * 64) * 8];
    for (int k0 = 0; k0 < K; k0 += 32) {
        __syncthreads();
        gl_lds16(gA + (size_t)r0 * K + k0 + o0, lA0);
        gl_lds16(gA + (size_t)r1 * K + k0 + o1, lA1);
        gl_lds16(gB + (size_t)r0 * K + k0 + o0, lB0);
        gl_lds16(gB + (size_t)r1 * K + k0 + o1, lB1);
        asm volatile("s_waitcnt vmcnt(0)" ::: "memory");
        __syncthreads();
        const int ko = (lane >> 4) * 8;
        const int ra = wr * 64 + (lane & 15);
        const int rb = wc * 64 + (lane & 15);
        bf16x8 af[4], bfv[4];
#pragma unroll
        for (int mi = 0; mi < 4; ++mi) af[mi] = *(const bf16x8*)&As[(ra + mi * 16) * 32 + ko];
#pragma unroll
        for (int ni = 0; ni < 4; ++ni) bfv[ni] = *(const bf16x8*)&Bs[(rb + ni * 16) * 32 + ko];
#pragma unroll
        for (int mi = 0; mi < 4; ++mi)
#pragma unroll
            for (int ni = 0; ni < 4; ++ni)
                acc[mi][ni] = __builtin_amdgcn_mfma_f32_16x16x32_bf16(af[mi], bfv[ni], acc[mi][ni], 0, 0, 0);
    }
    const int cl = lane & 15, r4 = (lane >> 4) * 4;
#pragma unroll
    for (int mi = 0; mi < 4; ++mi)
#pragma unroll
        for (int ni = 0; ni < 4; ++ni)
#pragma unroll
            for (int j = 0; j < 4; ++j) {
                const int r = m0 + wr * 64 + mi * 16 + r4 + j;
                const int c = n0 + wc * 64 + ni * 16 + cl;
                const float v = acc[mi][ni][j];
                if (EPI == 0) {
                    ((ushort_t*)C)[(size_t)r * N + c] = f2bf(v);
                } else if (EPI == 1) {
                    const int b = r >> 11, s = r & (SS - 1), h = c >> 7, d = c & 127;
                    ((ushort_t*)C)[(((size_t)(b * HH + h) * HDD + d) << 11) + s] = f2bf(v);
                } else {
                    const size_t idx = (size_t)r * N + c;
                    ((float*)C)[idx] = resid[idx] + v;
                }
            }
}

// ---------------------------------------------------------------------------
// Compacted-row down projection: C[perm[r]] += acc, branch weight by tile.
// A = act_c [RPAD][FF], Bt = wd [DD][FF] per branch. N=DD, K=FF.
// ---------------------------------------------------------------------------
__global__ __launch_bounds__(256, 2) void gemm_down_c(
    const ushort_t* __restrict__ A, const ushort_t* __restrict__ Bt_text,
    const ushort_t* __restrict__ Bt_audio, float* __restrict__ C,
    const int* __restrict__ perm, const int* __restrict__ header) {
    const int m0 = blockIdx.y * 128;
    if (m0 >= header[3]) return;           // beyond live rows
    const ushort_t* Bt = (m0 >= header[1]) ? Bt_audio : Bt_text;
    __shared__ ushort_t As[128 * 32];
    __shared__ ushort_t Bs[128 * 32];
    const int tid = threadIdx.x;
    const int w = tid >> 6, lane = tid & 63;
    const int n0 = blockIdx.x * 128;
    const int wr = w >> 1, wc = w & 1;
    f32x4 acc[4][4] = {};
    const ushort_t* gA = A + (size_t)m0 * FF;
    const ushort_t* gB = Bt + (size_t)n0 * FF;
    const int c0 = tid, c1 = 256 + tid;
    const int r0 = c0 >> 2, o0 = (c0 & 3) * 8;
    const int r1 = c1 >> 2, o1 = (c1 & 3) * 8;
    ushort_t* lA0 = &As[(w * 64) * 8];
    ushort_t* lA1 = &As[(256 + w * 64) * 8];
    ushort_t* lB0 = &Bs[(w * 64) * 8];
    ushort_t* lB1 = &Bs[(256 + w * 64) * 8];
    for (int k0 = 0; k0 < FF; k0 += 32) {
        __syncthreads();
        gl_lds16(gA + (size_t)r0 * FF + k0 + o0, lA0);
        gl_lds16(gA + (size_t)r1 * FF + k0 + o1, lA1);
        gl_lds16(gB + (size_t)r0 * FF + k0 + o0, lB0);
        gl_lds16(gB + (size_t)r1 * FF + k0 + o1, lB1);
        asm volatile("s_waitcnt vmcnt(0)" ::: "memory");
        __syncthreads();
        const int ko = (lane >> 4) * 8;
        const int ra = wr * 64 + (lane & 15);
        const int rb = wc * 64 + (lane & 15);
        bf16x8 af[4], bfv[4];
#pragma unroll
        for (int mi = 0; mi < 4; ++mi) af[mi] = *(const bf16x8*)&As[(ra + mi * 16) * 32 + ko];
#pragma unroll
        for (int ni = 0; ni < 4; ++ni) bfv[ni] = *(const bf16x8*)&Bs[(rb + ni * 16) * 32 + ko];
#pragma unroll
        for (int mi = 0; mi < 4; ++mi)
#pragma unroll
            for (int ni = 0; ni < 4; ++ni)
                acc[mi][ni] = __builtin_amdgcn_mfma_f32_16x16x32_bf16(af[mi], bfv[ni], acc[mi][ni], 0, 0, 0);
    }
    const int cl = lane & 15, r4 = (lane >> 4) * 4;
#pragma unroll
    for (int mi = 0; mi < 4; ++mi)
#pragma unroll
        for (int ni = 0; ni < 4; ++ni)
#pragma unroll
            for (int j = 0; j < 4; ++j) {
                const int r = m0 + wr * 64 + mi * 16 + r4 + j;
                const int p = perm[r];
                if (p >= 0) {
                    const int c = n0 + wc * 64 + ni * 16 + cl;
                    float* q = C + (size_t)p * DD + c;
                    *q = *q + acc[mi][ni][j];
                }
            }
}

// ---------------------------------------------------------------------------
// Compacted fused gate+up GEMM: 128(M) x 64(N per matrix); branch by tile.
// act_c[i][f] = silu(g)*u for compacted row i.
// ---------------------------------------------------------------------------
__global__ __launch_bounds__(256, 2) void gemm_gateup_c(
    const ushort_t* __restrict__ A,
    const ushort_t* __restrict__ Bg_text, const ushort_t* __restrict__ Bu_text,
    const ushort_t* __restrict__ Bg_audio, const ushort_t* __restrict__ Bu_audio,
    ushort_t* __restrict__ act, const int* __restrict__ header) {
    const int m0 = blockIdx.y * 128;
    if (m0 >= header[3]) return;
    const bool audio = (m0 >= header[1]);
    const ushort_t* Bg = audio ? Bg_audio : Bg_text;
    const ushort_t* Bu = audio ? Bu_audio : Bu_text;
    __shared__ ushort_t As[128 * 32];
    __shared__ ushort_t Bgs[64 * 32];
    __shared__ ushort_t Bus[64 * 32];
    const int tid = threadIdx.x, w = tid >> 6, lane = tid & 63;
    const int n0 = blockIdx.x * 64;
    const int wr = w >> 1, wc = w & 1;
    f32x4 ag[4][2] = {}, au[4][2] = {};
    const ushort_t* gA = A + (size_t)m0 * DD;
    const ushort_t* gG = Bg + (size_t)n0 * DD;
    const ushort_t* gU = Bu + (size_t)n0 * DD;
    const int c0 = tid, c1 = 256 + tid;
    const int rA0 = c0 >> 2, oA0 = (c0 & 3) * 8;
    const int rA1 = c1 >> 2, oA1 = (c1 & 3) * 8;
    ushort_t* lA0 = &As[(w * 64) * 8];
    ushort_t* lA1 = &As[(256 + w * 64) * 8];
    ushort_t* lG = &Bgs[(w * 64) * 8];
    ushort_t* lU = &Bus[(w * 64) * 8];
    for (int k0 = 0; k0 < DD; k0 += 32) {
        __syncthreads();
        gl_lds16(gA + (size_t)rA0 * DD + k0 + oA0, lA0);
        gl_lds16(gA + (size_t)rA1 * DD + k0 + oA1, lA1);
        gl_lds16(gG + (size_t)rA0 * DD + k0 + oA0, lG);
        gl_lds16(gU + (size_t)rA0 * DD + k0 + oA0, lU);
        asm volatile("s_waitcnt vmcnt(0)" ::: "memory");
        __syncthreads();
        const int ko = (lane >> 4) * 8;
        const int ra = wr * 64 + (lane & 15);
        const int rb = wc * 32 + (lane & 15);
        bf16x8 af[4], bg[2], bu[2];
#pragma unroll
        for (int mi = 0; mi < 4; ++mi) af[mi] = *(const bf16x8*)&As[(ra + mi * 16) * 32 + ko];
#pragma unroll
        for (int ni = 0; ni < 2; ++ni) {
            bg[ni] = *(const bf16x8*)&Bgs[(rb + ni * 16) * 32 + ko];
            bu[ni] = *(const bf16x8*)&Bus[(rb + ni * 16) * 32 + ko];
        }
#pragma unroll
        for (int mi = 0; mi < 4; ++mi)
#pragma unroll
            for (int ni = 0; ni < 2; ++ni) {
                ag[mi][ni] = __builtin_amdgcn_mfma_f32_16x16x32_bf16(af[mi], bg[ni], ag[mi][ni], 0, 0, 0);
                au[mi][ni] = __builtin_amdgcn_mfma_f32_16x16x32_bf16(af[mi], bu[ni], au[mi][ni], 0, 0, 0);
            }
    }
    const int cl = lane & 15, r4 = (lane >> 4) * 4;
#pragma unroll
    for (int mi = 0; mi < 4; ++mi)
#pragma unroll
        for (int ni = 0; ni < 2; ++ni)
#pragma unroll
            for (int j = 0; j < 4; ++j) {
                const int r = m0 + wr * 64 + mi * 16 + r4 + j;
                const int c = n0 + wc * 32 + ni * 16 + cl;
                const float g = ag[mi][ni][j], u = au[mi][ni][j];
                const float sv = g / (1.0f + __expf(-g)) * u;
                act[(size_t)r * FF + c] = f2bf(sv);
            }
}

// ---------------------------------------------------------------------------
// Causal flash attention. grid (S/64, B*H). 4 waves, each owns 16 q-rows.
// ---------------------------------------------------------------------------
__global__ __launch_bounds__(256, 2) void attn_k(
    const ushort_t* __restrict__ qb, const ushort_t* __restrict__ kb,
    const ushort_t* __restrict__ vt, ushort_t* __restrict__ ctx) {
    __shared__ ushort_t Ks[64 * 128];   // [sk][d]
    __shared__ ushort_t Vs[128 * 64];   // [d][sk]
    __shared__ ushort_t Pw[4][16 * 64]; // per-wave P transpose buffer
    const int tid = threadIdx.x, w = tid >> 6, lane = tid & 63;
    const int qt = blockIdx.x, bh = blockIdx.y, b = bh >> 4, h = bh & 15;
    const int q0 = qt * 64 + w * 16;
    bf16x8 aq[4];
    {
        const ushort_t* qr = qb + ((size_t)(b * SS + q0 + (lane & 15))) * DD + h * HDD + (lane >> 4) * 8;
#pragma unroll
        for (int ko = 0; ko < 4; ++ko) aq[ko] = *(const bf16x8*)(qr + ko * 32);
    }
    f32x4 o[8] = {};
    float mrow[4] = {-3e38f, -3e38f, -3e38f, -3e38f};
    float lrow[4] = {};
    for (int kt = 0; kt <= qt; ++kt) {
        const int sk0 = kt * 64;
        __syncthreads();
#pragma unroll
        for (int i = 0; i < 4; ++i) {
            const int c = i * 256 + tid;
            gl_lds16(kb + ((size_t)(b * SS + sk0 + (c >> 4))) * DD + h * HDD + (c & 15) * 8,
                     &Ks[(i * 256 + w * 64) * 8]);
        }
#pragma unroll
        for (int i = 0; i < 4; ++i) {
            const int c = i * 256 + tid;
            gl_lds16(vt + ((size_t)((b * HH + h) * HDD + (c >> 3))) * SS + sk0 + (c & 7) * 8,
                     &Vs[(i * 256 + w * 64) * 8]);
        }
        asm volatile("s_waitcnt vmcnt(0)" ::: "memory");
        __syncthreads();
        f32x4 s[4] = {};
#pragma unroll
        for (int ko = 0; ko < 4; ++ko)
#pragma unroll
            for (int ni = 0; ni < 4; ++ni) {
                bf16x8 bk = *(const bf16x8*)&Ks[(ni * 16 + (lane & 15)) * 128 + ko * 32 + (lane >> 4) * 8];
                s[ni] = __builtin_amdgcn_mfma_f32_16x16x32_bf16(aq[ko], bk, s[ni], 0, 0, 0);
            }
        const float scale = 0.08838834764831843f;  // 1/sqrt(128)
        const bool diag = (kt == qt);
#pragma unroll
        for (int ni = 0; ni < 4; ++ni)
#pragma unroll
            for (int j = 0; j < 4; ++j) {
                float v = s[ni][j] * scale;
                if (diag) {
                    const int kg = ni * 16 + (lane & 15);
                    const int qg = w * 16 + (lane >> 4) * 4 + j;
                    if (kg > qg) v = -1e30f;
                }
                s[ni][j] = v;
            }
#pragma unroll
        for (int j = 0; j < 4; ++j) {
            float tm = fmaxf(fmaxf(s[0][j], s[1][j]), fmaxf(s[2][j], s[3][j]));
#pragma unroll
            for (int dd = 1; dd < 16; dd <<= 1) tm = fmaxf(tm, __shfl_xor(tm, dd));
            const float mn = fmaxf(mrow[j], tm);
            const float corr = __expf(mrow[j] - mn);
            float sum = 0.f;
#pragma unroll
            for (int ni = 0; ni < 4; ++ni) {
                const float p = __expf(s[ni][j] - mn);
                s[ni][j] = p;
                sum += p;
            }
#pragma unroll
            for (int dd = 1; dd < 16; dd <<= 1) sum += __shfl_xor(sum, dd);
            lrow[j] = lrow[j] * corr + sum;
            mrow[j] = mn;
#pragma unroll
            for (int di = 0; di < 8; ++di) o[di][j] *= corr;
        }
#pragma unroll
        for (int ni = 0; ni < 4; ++ni)
#pragma unroll
            for (int j = 0; j < 4; ++j)
                Pw[w][((lane >> 4) * 4 + j) * 64 + ni * 16 + (lane & 15)] = f2bf(s[ni][j]);
#pragma unroll
        for (int ks = 0; ks < 2; ++ks) {
            bf16x8 pa = *(const bf16x8*)&Pw[w][(lane & 15) * 64 + ks * 32 + (lane >> 4) * 8];
#pragma unroll
            for (int di = 0; di < 8; ++di) {
                bf16x8 bv = *(const bf16x8*)&Vs[(di * 16 + (lane & 15)) * 64 + ks * 32 + (lane >> 4) * 8];
                o[di] = __builtin_amdgcn_mfma_f32_16x16x32_bf16(pa, bv, o[di], 0, 0, 0);
            }
        }
    }
    float inv[4];
#pragma unroll
    for (int j = 0; j < 4; ++j) inv[j] = 1.0f / lrow[j];
#pragma unroll
    for (int di = 0; di < 8; ++di)
#pragma unroll
        for (int j = 0; j < 4; ++j) {
            const int r = q0 + (lane >> 4) * 4 + j;
            ctx[((size_t)(b * SS + r)) * DD + h * HDD + di * 16 + (lane & 15)] = f2bf(o[di][j] * inv[j]);
        }
}

// ---------------------------------------------------------------------------
extern "C" void kernel_launch(void* const* d_in, const int* in_sizes, int n_in,
                              void* d_out, int out_size, void* d_ws, size_t ws_size,
                              hipStream_t stream) {
    (void)in_sizes; (void)n_in; (void)out_size; (void)ws_size;
    const float* hs  = (const float*)d_in[0];
    const unsigned char* mask_raw = (const unsigned char*)d_in[1];
    const float* wq  = (const float*)d_in[2];
    const float* wk  = (const float*)d_in[3];
    const float* wv  = (const float*)d_in[4];
    const float* wo  = (const float*)d_in[5];
    const float* iln = (const float*)d_in[6];
    const float* pln = (const float*)d_in[7];
    const float* aln = (const float*)d_in[8];
    const float* wgt = (const float*)d_in[9];
    const float* wut = (const float*)d_in[10];
    const float* wdt = (const float*)d_in[11];
    const float* wga = (const float*)d_in[12];
    const float* wua = (const float*)d_in[13];
    const float* wda = (const float*)d_in[14];

    const size_t SZ_W1 = (size_t)DD * DD * 2;       // 8 MB
    const size_t SZ_W2 = (size_t)DD * FF * 2;       // 32 MB
    const size_t SZ_A  = (size_t)TT * DD * 2;       // 16 MB

    char* ws = (char*)d_ws;
    size_t off = 0;
    auto take = [&](size_t n) { char* p = ws + off; off += n; return p; };
    ushort_t* wq_t  = (ushort_t*)take(SZ_W1);
    ushort_t* wk_t  = (ushort_t*)take(SZ_W1);
    ushort_t* wv_t  = (ushort_t*)take(SZ_W1);
    ushort_t* wo_t  = (ushort_t*)take(SZ_W1);
    ushort_t* wg_tb = (ushort_t*)take(SZ_W2);
    ushort_t* wu_tb = (ushort_t*)take(SZ_W2);
    ushort_t* wd_tb = (ushort_t*)take(SZ_W2);
    ushort_t* wg_ab = (ushort_t*)take(SZ_W2);
    ushort_t* wu_ab = (ushort_t*)take(SZ_W2);
    ushort_t* wd_ab = (ushort_t*)take(SZ_W2);
    char* actreg = take(6 * SZ_A);                  // 96 MB region, multi-use
    float* cosb = (float*)take((size_t)SS * 64 * 4);
    float* sinb = (float*)take((size_t)SS * 64 * 4);
    unsigned char* mask = (unsigned char*)take(TT);
    int* perm   = (int*)take(RPAD * 4);
    int* header = (int*)take(64);

    // phase-1 overlays of actreg (attention):
    ushort_t* h_bf = (ushort_t*)(actreg);
    ushort_t* qb   = (ushort_t*)(actreg + 1 * SZ_A);
    ushort_t* kb   = (ushort_t*)(actreg + 2 * SZ_A);
    ushort_t* vt   = (ushort_t*)(actreg + 3 * SZ_A);
    ushort_t* ctx  = (ushort_t*)(actreg + 4 * SZ_A);
    // phase-2 overlays (FFN, after attention consumers are done):
    ushort_t* hn_c  = (ushort_t*)(actreg);                              // RPAD x DD bf16 (17.8 MB)
    ushort_t* act_c = (ushort_t*)(actreg + (size_t)RPAD * DD * 2);      // RPAD x FF bf16 (71.3 MB)

    const dim3 blk(256);

    norm_mask<<<1, blk, 0, stream>>>(mask_raw, mask);
    partition_k<<<1, blk, 0, stream>>>(mask, perm, header);

    // --- weight convert + transpose to bf16 [N][K] ---
    convw<<<dim3(DD / 32, DD / 32), blk, 0, stream>>>(wq, wq_t, DD, DD);
    convw<<<dim3(DD / 32, DD / 32), blk, 0, stream>>>(wk, wk_t, DD, DD);
    convw<<<dim3(DD / 32, DD / 32), blk, 0, stream>>>(wv, wv_t, DD, DD);
    convw<<<dim3(DD / 32, DD / 32), blk, 0, stream>>>(wo, wo_t, DD, DD);
    convw<<<dim3(FF / 32, DD / 32), blk, 0, stream>>>(wgt, wg_tb, DD, FF);
    convw<<<dim3(FF / 32, DD / 32), blk, 0, stream>>>(wut, wu_tb, DD, FF);
    convw<<<dim3(DD / 32, FF / 32), blk, 0, stream>>>(wdt, wd_tb, FF, DD);
    convw<<<dim3(FF / 32, DD / 32), blk, 0, stream>>>(wga, wg_ab, DD, FF);
    convw<<<dim3(FF / 32, DD / 32), blk, 0, stream>>>(wua, wu_ab, DD, FF);
    convw<<<dim3(DD / 32, FF / 32), blk, 0, stream>>>(wda, wd_ab, FF, DD);

    rope_tab<<<(SS * 64) / 256, blk, 0, stream>>>(cosb, sinb);

    // --- attention block ---
    rmsnorm_k<<<TT, blk, 0, stream>>>(hs, iln, h_bf);
    gemm_nt<0><<<dim3(DD / 128, TT / 128), blk, 0, stream>>>(h_bf, wq_t, TT, DD, DD, qb, nullptr);
    gemm_nt<0><<<dim3(DD / 128, TT / 128), blk, 0, stream>>>(h_bf, wk_t, TT, DD, DD, kb, nullptr);
    gemm_nt<1><<<dim3(DD / 128, TT / 128), blk, 0, stream>>>(h_bf, wv_t, TT, DD, DD, vt, nullptr);
    rope_apply<<<(TT * 1024) / 256, blk, 0, stream>>>(qb, cosb, sinb);
    rope_apply<<<(TT * 1024) / 256, blk, 0, stream>>>(kb, cosb, sinb);
    attn_k<<<dim3(SS / 64, BB * HH), blk, 0, stream>>>(qb, kb, vt, ctx);
    // d_out = hidden = residual + ctx @ wo
    gemm_nt<2><<<dim3(DD / 128, TT / 128), blk, 0, stream>>>(ctx, wo_t, TT, DD, DD, d_out, hs);

    // --- routed dual FFN on compacted rows ---
    rmsnorm_gather<<<RPAD, blk, 0, stream>>>((const float*)d_out, pln, aln, perm, header, hn_c);
    gemm_gateup_c<<<dim3(FF / 64, RPAD / 128), blk, 0, stream>>>(hn_c, wg_tb, wu_tb, wg_ab, wu_ab, act_c, header);
    gemm_down_c<<<dim3(DD / 128, RPAD / 128), blk, 0, stream>>>(act_c, wd_tb, wd_ab, (float*)d_out, perm, header);
}